// Round 1
// 105.695 us; speedup vs baseline: 1.0399x; 1.0399x over previous
//
#include <hip/hip_runtime.h>
#include <hip/hip_bf16.h>

// ---------------------------------------------------------------------------
// KroneNet fused kernel v9 for MI355X (gfx950)
// out[i][j] = softmax_j( s_a[i] * t_j[i] )
// History: v4 46.5us / v5 151us (spill) / v6 46us 2-dispatch / v7 50us /
// v8 40.9us kernel (VALU-issue-bound: MfmaUtil 15%, VALUBusy 48%).
// v9: pure VALU-inst-count cuts, register-neutral (must hold 64 arch VGPR +
// 64 AGPR = 128 total for 2 blocks/CU):
//   - pack2bf: 3 VALU -> 1 via v_cvt_pk_bf16_f32 (RNE, inline asm; T12)
//   - redcol: ds_swizzle shuffles -> DPP-fused v_add_f32 (8 -> 4 insts,
//     off the LDS pipe; mirror ctrls are xor4/xor8-equivalent after the
//     xor1/xor2 stages, bit-exact)
//   - W3b stored transposed [n][4]: 1 ds_read_b128 per (mt,t) instead of
//     3 strided b32 (48 -> 16 LDS reads/chunk)
//   - W1b/B2b/W3a/W3b staged up front; phase transition = sync, W2 repack,
//     sync only
// ---------------------------------------------------------------------------

#define BTOT 262144
#define NBLK (BTOT / 512)   // 512 blocks x 512 samples (8 waves x 64)

typedef __attribute__((ext_vector_type(4))) float floatx4;
typedef __attribute__((ext_vector_type(8))) short bf16x8;
typedef __attribute__((ext_vector_type(4))) int  intx4;

// LDS layout (bytes)
#define OFF_W2   0          // 4 ksteps * 8 ntiles * 64 lanes * 16B = 32768
#define OFF_W1A  32768      // 144 float4 slots                     = 2304
#define OFF_W1B  35072      // 144 float4 slots                     = 2304
#define OFF_B2A  37376      // 128 * float                          = 512
#define OFF_B2B  37888      // 128 * float                          = 512
#define OFF_W3A  38400      // 128 * float                          = 512
#define OFF_W3B  38912      // 128 * float4 (transposed [n][j])     = 2048
#define OFF_SA   40960      // 512 * float (s_a per sample)         = 2048
#define LDS_TOTAL 43008

// pack two fp32 -> one dword of two bf16, single VALU op (RNE rounding)
static __device__ __forceinline__ int pack2bf(float lo, float hi) {
    int r;
    asm("v_cvt_pk_bf16_f32 %0, %1, %2" : "=v"(r) : "v"(lo), "v"(hi));
    return r;
}

// compile-time-indexed 4-way select (NO dynamic register indexing)
#define SEL4(a0, a1, a2, a3, i) \
    ((i) == 0 ? (a0) : (i) == 1 ? (a1) : (i) == 2 ? (a2) : (a3))

// DPP-fused butterfly add: v += lanes-permuted(v), 1 VALU inst per stage.
// 0xB1 = quad_perm [1,0,3,2] (xor1), 0x4E = quad_perm [2,3,0,1] (xor2),
// 0x141 = row_half_mirror (== xor4 after xor1/xor2 stages),
// 0x140 = row_mirror      (== xor8 after the first three stages)
template <int CTRL>
static __device__ __forceinline__ float dppadd(float v) {
    int t = __builtin_amdgcn_update_dpp(0, __builtin_bit_cast(int, v),
                                        CTRL, 0xF, 0xF, true);
    return v + __builtin_bit_cast(float, t);
}
static __device__ __forceinline__ float redcol(float v) {
    v = dppadd<0xB1>(v);
    v = dppadd<0x4E>(v);
    v = dppadd<0x141>(v);
    v = dppadd<0x140>(v);
    return v;
}

// W1 slot with bank-conflict padding: one extra float4 slot every 8 entries
static __device__ __forceinline__ int w1slot(int k) { return k + (k >> 3); }

// Pack one path's W2 into LDS (512 threads, 8 iters).
// W2 mapping (verified v5-v8): float4 group u = n*32+k4, k = 4*k4:
// dest = (s*8+t)*1024 + l*16 + (k&7)*2, s=k>>5, l=((k&31)>>3)*16+(n&15),
// t = n>>4.  Lane remap: n = (tid&15)|(i<<4), k4 = tid>>4 -> <=4-way
// write conflicts.
static __device__ __forceinline__ void pack_w2(
        unsigned char* smem, int tid, const float* __restrict__ w2) {
    const float4* w2p = (const float4*)w2;
    #pragma unroll
    for (int i = 0; i < 8; ++i) {
        int n  = (tid & 15) | (i << 4);
        int k4 = tid >> 4;
        float4 f = w2p[n * 32 + k4];
        int k = k4 * 4;
        int s = k >> 5;
        int j0 = k & 7;               // 0 or 4
        int l = ((k & 31) >> 3) * 16 + (n & 15);
        int2 pkd;
        pkd.x = pack2bf(f.x, f.y);
        pkd.y = pack2bf(f.z, f.w);
        *(int2*)(smem + OFF_W2 + (s * 8 + (n >> 4)) * 1024 + l * 16 + j0 * 2) = pkd;
    }
}

static __device__ __forceinline__ void stage_small(
        unsigned char* smem, int tid, int offW1, int offB2,
        const float* __restrict__ w1, const float* __restrict__ b1,
        const float* __restrict__ b2) {
    if (tid < 128) {
        ((float4*)(smem + offW1))[w1slot(tid)] =
            make_float4(w1[2 * tid], w1[2 * tid + 1], b1[tid], 0.f);
        ((float*)(smem + offB2))[tid] = b2[tid];
    }
}

// One chunk's GEMM: acc = W2 . relu(W1.x+b1) + b2 (acc pre-init with b2).
// acc layout: (t, mt, r) -> sample mt*16+quad*4+r, n = t*16+col.
#define GEMM_CHUNK(acc, XV, W1p, W2p, B2p)                                     \
    {                                                                          \
        _Pragma("unroll")                                                      \
        for (int t = 0; t < 8; ++t) {                                          \
            float b2n = (B2p)[t * 16 + col];                                   \
            floatx4 bi = (floatx4){b2n, b2n, b2n, b2n};                        \
            _Pragma("unroll")                                                  \
            for (int mt = 0; mt < 2; ++mt) acc[t][mt] = bi;                    \
        }                                                                      \
        _Pragma("unroll")                                                      \
        for (int s = 0; s < 4; ++s) {                                          \
            intx4 af[2];                                                       \
            const int bslot = s * 36 + quad * 9;                               \
            _Pragma("unroll")                                                  \
            for (int j2 = 0; j2 < 4; ++j2) {                                   \
                float4 c0 = (W1p)[bslot + 2 * j2];                             \
                float4 c1 = (W1p)[bslot + 2 * j2 + 1];                         \
                _Pragma("unroll")                                              \
                for (int mt = 0; mt < 2; ++mt) {                               \
                    float h0 = fmaxf(fmaf((XV)[mt].x, c0.x,                    \
                                fmaf((XV)[mt].y, c0.y, c0.z)), 0.f);           \
                    float h1 = fmaxf(fmaf((XV)[mt].x, c1.x,                    \
                                fmaf((XV)[mt].y, c1.y, c1.z)), 0.f);           \
                    af[mt][j2] = pack2bf(h0, h1);                              \
                }                                                              \
            }                                                                  \
            _Pragma("unroll")                                                  \
            for (int t = 0; t < 8; ++t) {                                      \
                bf16x8 bfr = (W2p)[(s * 8 + t) * 64 + lane];                   \
                _Pragma("unroll")                                              \
                for (int mt = 0; mt < 2; ++mt)                                 \
                    acc[t][mt] = __builtin_amdgcn_mfma_f32_16x16x32_bf16(      \
                        __builtin_bit_cast(bf16x8, af[mt]), bfr,               \
                        acc[t][mt], 0, 0, 0);                                  \
            }                                                                  \
        }                                                                      \
    }

// ---------------------------------------------------------------------------
// 512 blocks x 512 threads (8 waves). Per block (512 samples):
//   stage everything small + pack W2a -> phase a (s_a -> LDS)
//   repack W2b only -> phase b (t_j, softmax with LDS s_a, store out)
// ---------------------------------------------------------------------------
__global__ __launch_bounds__(512, 4)
void krone_fused(const float* __restrict__ x,
                 const float* __restrict__ w1a, const float* __restrict__ w1b,
                 const float* __restrict__ b1a, const float* __restrict__ b1b,
                 const float* __restrict__ w2a, const float* __restrict__ w2b,
                 const float* __restrict__ b2a, const float* __restrict__ b2b,
                 const float* __restrict__ w3a, const float* __restrict__ w3b,
                 const float* __restrict__ b3a, const float* __restrict__ b3b,
                 float* __restrict__ out) {
    __shared__ __align__(16) unsigned char smem[LDS_TOTAL];

    const int tid  = threadIdx.x;
    const int lane = tid & 63;
    const int wave = tid >> 6;
    const int quad = lane >> 4;
    const int col  = lane & 15;
    const int wbase = blockIdx.x * 512 + wave * 64;   // this wave's 64 samples

    const bf16x8* W2  = (const bf16x8*)(smem + OFF_W2);
    const float4* W1A = (const float4*)(smem + OFF_W1A);
    const float4* W1B = (const float4*)(smem + OFF_W1B);
    const float*  B2A = (const float*)(smem + OFF_B2A);
    const float*  B2B = (const float*)(smem + OFF_B2B);
    const float*  W3A = (const float*)(smem + OFF_W3A);
    const float4* W3T = (const float4*)(smem + OFF_W3B);
    float*        SA  = (float*)(smem + OFF_SA);
    const float2* xA = (const float2*)x;
    const float2* xB = xA + BTOT;

    const float b3a_ = b3a[0];                        // uniform -> SGPR
    const float b30 = b3b[0], b31 = b3b[1], b32 = b3b[2];

    // ---- stage: x(a) loads + ALL small weight buffers + W2a pack ----
    float2 xv[4];   // [c*2+mt], phase-a x (8 VGPRs)
    #pragma unroll
    for (int c = 0; c < 2; ++c)
        #pragma unroll
        for (int mt = 0; mt < 2; ++mt)
            xv[c * 2 + mt] = xA[wbase + c * 32 + mt * 16 + col];

    pack_w2(smem, tid, w2a);
    stage_small(smem, tid, OFF_W1A, OFF_B2A, w1a, b1a, b2a);
    stage_small(smem, tid, OFF_W1B, OFF_B2B, w1b, b1b, b2b);
    if (tid < 128) ((float*)(smem + OFF_W3A))[tid] = w3a[tid];
    if (tid < 384) {                                  // transpose w3b [3][128]
        int j = tid >> 7, n = tid & 127;              //  -> [128][4] floats
        ((float*)(smem + OFF_W3B))[n * 4 + j] = w3b[tid];
    }
    __syncthreads();

    // ---- phase a ----
    #pragma unroll
    for (int c = 0; c < 2; ++c) {
        __builtin_amdgcn_sched_barrier(0);
        floatx4 acc[8][2];
        GEMM_CHUNK(acc, xv + 2 * c, W1A, W2, B2A);
        __builtin_amdgcn_sched_barrier(0);

        float pa[2][4] = {};
        #pragma unroll
        for (int t = 0; t < 8; ++t) {
            float w3n = W3A[t * 16 + col];
            #pragma unroll
            for (int mt = 0; mt < 2; ++mt)
                #pragma unroll
                for (int r = 0; r < 4; ++r)
                    pa[mt][r] = fmaf(w3n, fmaxf(acc[t][mt][r], 0.f), pa[mt][r]);
        }
        #pragma unroll
        for (int mt = 0; mt < 2; ++mt)
            #pragma unroll
            for (int r = 0; r < 4; ++r) pa[mt][r] = redcol(pa[mt][r]);
        __builtin_amdgcn_sched_barrier(0);

        if (col < 4) {
            #pragma unroll
            for (int mt = 0; mt < 2; ++mt) {
                int sl = mt * 16 + quad * 4 + col;
                SA[wave * 64 + c * 32 + sl] =
                    SEL4(pa[mt][0], pa[mt][1], pa[mt][2], pa[mt][3], col) + b3a_;
            }
        }
        __builtin_amdgcn_sched_barrier(0);
    }

    // ---- phase b: reload x, repack W2 only, compute, softmax ----
    #pragma unroll
    for (int c = 0; c < 2; ++c)
        #pragma unroll
        for (int mt = 0; mt < 2; ++mt)
            xv[c * 2 + mt] = xB[wbase + c * 32 + mt * 16 + col];

    __syncthreads();   // everyone done reading W2a
    pack_w2(smem, tid, w2b);
    __syncthreads();

    #pragma unroll
    for (int c = 0; c < 2; ++c) {
        __builtin_amdgcn_sched_barrier(0);
        floatx4 acc[8][2];
        GEMM_CHUNK(acc, xv + 2 * c, W1B, W2, B2B);
        __builtin_amdgcn_sched_barrier(0);

        #pragma unroll
        for (int mt = 0; mt < 2; ++mt) {     // per-mt: 12 live partials
            float p0[4] = {}, p1[4] = {}, p2[4] = {};
            #pragma unroll
            for (int t = 0; t < 8; ++t) {
                float4 w3v = W3T[t * 16 + col];   // one b128: {w30,w31,w32,-}
                #pragma unroll
                for (int r = 0; r < 4; ++r) {
                    float h = fmaxf(acc[t][mt][r], 0.f);
                    p0[r] = fmaf(w3v.x, h, p0[r]);
                    p1[r] = fmaf(w3v.y, h, p1[r]);
                    p2[r] = fmaf(w3v.z, h, p2[r]);
                }
            }
            #pragma unroll
            for (int r = 0; r < 4; ++r) {
                p0[r] = redcol(p0[r]);
                p1[r] = redcol(p1[r]);
                p2[r] = redcol(p2[r]);
            }
            if (col < 4) {
                int sl = mt * 16 + quad * 4 + col;
                float t0 = SEL4(p0[0], p0[1], p0[2], p0[3], col) + b30;
                float t1 = SEL4(p1[0], p1[1], p1[2], p1[3], col) + b31;
                float t2 = SEL4(p2[0], p2[1], p2[2], p2[3], col) + b32;
                float sa = SA[wave * 64 + c * 32 + sl];
                float y0 = sa * t0, y1 = sa * t1, y2 = sa * t2;
                float m = fmaxf(y0, fmaxf(y1, y2));
                float e0 = __expf(y0 - m), e1 = __expf(y1 - m), e2 = __expf(y2 - m);
                float rs = 1.f / (e0 + e1 + e2);
                long o = (long)(wbase + c * 32 + sl) * 3;
                out[o]     = e0 * rs;
                out[o + 1] = e1 * rs;
                out[o + 2] = e2 * rs;
            }
        }
        __builtin_amdgcn_sched_barrier(0);
    }
}

extern "C" void kernel_launch(void* const* d_in, const int* in_sizes, int n_in,
                              void* d_out, int out_size, void* d_ws, size_t ws_size,
                              hipStream_t stream) {
    const float* x   = (const float*)d_in[0];
    const float* w1a = (const float*)d_in[1];
    const float* w1b = (const float*)d_in[2];
    const float* b1a = (const float*)d_in[3];
    const float* b1b = (const float*)d_in[4];
    const float* w2a = (const float*)d_in[5];
    const float* w2b = (const float*)d_in[6];
    const float* b2a = (const float*)d_in[7];
    const float* b2b = (const float*)d_in[8];
    const float* w3a = (const float*)d_in[9];
    const float* w3b = (const float*)d_in[10];
    const float* b3a = (const float*)d_in[11];
    const float* b3b = (const float*)d_in[12];
    float* out = (float*)d_out;

    krone_fused<<<NBLK, 512, 0, stream>>>(x, w1a, w1b, b1a, b1b, w2a, w2b,
                                          b2a, b2b, w3a, w3b, b3a, b3b, out);
}